// Round 1
// baseline (2691.496 us; speedup 1.0000x reference)
//
#include <hip/hip_runtime.h>

#define DFEAT 64

__global__ void k_init_deg(float* __restrict__ deg, int N) {
    int i = blockIdx.x * blockDim.x + threadIdx.x;
    if (i < N) deg[i] = 1.0f;  // self-loop
}

__global__ void k_count(const int* __restrict__ dst, float* __restrict__ deg, int E) {
    int e = blockIdx.x * blockDim.x + threadIdx.x;
    if (e < E) atomicAdd(&deg[dst[e]], 1.0f);
}

__global__ void k_dinv(float* __restrict__ deg, int N) {
    int i = blockIdx.x * blockDim.x + threadIdx.x;
    if (i < N) deg[i] = rsqrtf(deg[i]);  // deg >= 1 always (self-loop)
}

// g[n][c] = (h[n,:] @ W[:,c]) * dinv[n];  acc initialized to g (self-loop term)
__global__ void k_gemm_scale(const float* __restrict__ h, const float* __restrict__ W,
                             const float* __restrict__ dinv, float* __restrict__ g,
                             float* __restrict__ acc, int N) {
    __shared__ float Wl[DFEAT * DFEAT];
    int tid = threadIdx.x;
    #pragma unroll
    for (int i = 0; i < 16; ++i) Wl[tid + i * 256] = W[tid + i * 256];
    __syncthreads();

    int row = blockIdx.x * 4 + (tid >> 6);
    int col = tid & 63;
    if (row >= N) return;

    const float4* h4 = reinterpret_cast<const float4*>(h + (size_t)row * DFEAT);
    float s = 0.f;
    #pragma unroll
    for (int k4 = 0; k4 < 16; ++k4) {
        float4 hv = h4[k4];  // wave-uniform address (row uniform per wave) -> broadcast
        s += hv.x * Wl[(k4 * 4 + 0) * 64 + col];
        s += hv.y * Wl[(k4 * 4 + 1) * 64 + col];
        s += hv.z * Wl[(k4 * 4 + 2) * 64 + col];
        s += hv.w * Wl[(k4 * 4 + 3) * 64 + col];
    }
    s *= dinv[row];
    int o = row * DFEAT + col;
    g[o] = s;
    acc[o] = s;
}

// 16 threads per edge: each handles 4 consecutive feature floats.
__global__ void k_scatter(const int* __restrict__ src, const int* __restrict__ dst,
                          const float* __restrict__ g, float* __restrict__ acc, int E) {
    int tid = blockIdx.x * blockDim.x + threadIdx.x;
    if (tid >= E * 16) return;
    int e = tid >> 4, q = tid & 15;
    int s = src[e], d = dst[e];
    float4 v = reinterpret_cast<const float4*>(g)[s * 16 + q];
    float* a = acc + (size_t)d * DFEAT + q * 4;
    atomicAdd(a + 0, v.x);
    atomicAdd(a + 1, v.y);
    atomicAdd(a + 2, v.z);
    atomicAdd(a + 3, v.w);
}

// h_out = relu(dinv[n] * acc + b)
__global__ void k_finalize(const float* __restrict__ acc, const float* __restrict__ dinv,
                           const float* __restrict__ b, float* __restrict__ hout, int N) {
    int tid = blockIdx.x * blockDim.x + threadIdx.x;
    if (tid >= N * 16) return;
    int n = tid >> 4, q = tid & 15;
    float di = dinv[n];
    float4 a = reinterpret_cast<const float4*>(acc)[tid];
    float4 bb = reinterpret_cast<const float4*>(b)[q];
    float4 r;
    r.x = fmaxf(fmaf(di, a.x, bb.x), 0.f);
    r.y = fmaxf(fmaf(di, a.y, bb.y), 0.f);
    r.z = fmaxf(fmaf(di, a.z, bb.z), 0.f);
    r.w = fmaxf(fmaf(di, a.w, bb.w), 0.f);
    reinterpret_cast<float4*>(hout)[tid] = r;
}

extern "C" void kernel_launch(void* const* d_in, const int* in_sizes, int n_in,
                              void* d_out, int out_size, void* d_ws, size_t ws_size,
                              hipStream_t stream) {
    const float* x  = (const float*)d_in[0];
    const float* W1 = (const float*)d_in[1];
    const float* b1 = (const float*)d_in[2];
    const float* W2 = (const float*)d_in[3];
    const float* b2 = (const float*)d_in[4];
    const float* W3 = (const float*)d_in[5];
    const float* b3 = (const float*)d_in[6];
    const int* eidx = (const int*)d_in[7];  // jnp.int64 -> int32 under default JAX config

    const int N = in_sizes[0] / DFEAT;   // 100000
    const int E = in_sizes[7] / 2;       // 1000000
    const int* esrc = eidx;
    const int* edst = eidx + E;

    float* ws   = (float*)d_ws;
    float* dinv = ws;                       // N floats (deg -> dinv in place)
    float* g    = ws + N;                   // N*64
    float* acc  = g + (size_t)N * DFEAT;    // N*64
    float* hbuf = acc + (size_t)N * DFEAT;  // N*64
    float* out  = (float*)d_out;

    const int B = 256;
    dim3 blk(B);

    // degree + dinv (reused for all 3 layers)
    k_init_deg<<<(N + B - 1) / B, blk, 0, stream>>>(dinv, N);
    k_count<<<(E + B - 1) / B, blk, 0, stream>>>(edst, dinv, E);
    k_dinv<<<(N + B - 1) / B, blk, 0, stream>>>(dinv, N);

    const int gemm_grid = (N + 3) / 4;
    const int scat_grid = (E * 16 + B - 1) / B;
    const int fin_grid  = (N * 16 + B - 1) / B;

    // layer 1
    k_gemm_scale<<<gemm_grid, blk, 0, stream>>>(x, W1, dinv, g, acc, N);
    k_scatter<<<scat_grid, blk, 0, stream>>>(esrc, edst, g, acc, E);
    k_finalize<<<fin_grid, blk, 0, stream>>>(acc, dinv, b1, hbuf, N);
    // layer 2
    k_gemm_scale<<<gemm_grid, blk, 0, stream>>>(hbuf, W2, dinv, g, acc, N);
    k_scatter<<<scat_grid, blk, 0, stream>>>(esrc, edst, g, acc, E);
    k_finalize<<<fin_grid, blk, 0, stream>>>(acc, dinv, b2, hbuf, N);
    // layer 3
    k_gemm_scale<<<gemm_grid, blk, 0, stream>>>(hbuf, W3, dinv, g, acc, N);
    k_scatter<<<scat_grid, blk, 0, stream>>>(esrc, edst, g, acc, E);
    k_finalize<<<fin_grid, blk, 0, stream>>>(acc, dinv, b3, out, N);
}

// Round 2
// 453.059 us; speedup vs baseline: 5.9407x; 5.9407x over previous
//
#include <hip/hip_runtime.h>

#define DFEAT 64
#define SCAN_B 1024

// ---------- degree / dinv ----------
__global__ void k_zero_deg(int* __restrict__ deg, int N) {
    int i = blockIdx.x * blockDim.x + threadIdx.x;
    if (i < N) deg[i] = 0;
}

__global__ void k_hist(const int* __restrict__ dst, int* __restrict__ deg, int E) {
    int e = blockIdx.x * blockDim.x + threadIdx.x;
    if (e < E) atomicAdd(&deg[dst[e]], 1);
}

__global__ void k_dinv(const int* __restrict__ deg, float* __restrict__ dinv, int N) {
    int i = blockIdx.x * blockDim.x + threadIdx.x;
    if (i < N) dinv[i] = rsqrtf(1.0f + (float)deg[i]);  // +1 = self-loop
}

// ---------- exclusive scan of deg -> rowstart ----------
__global__ void k_scan_block(const int* __restrict__ deg, int* __restrict__ excl,
                             int* __restrict__ blockSums, int N) {
    __shared__ int sm[SCAN_B];
    int gid = blockIdx.x * SCAN_B + threadIdx.x;
    int v = (gid < N) ? deg[gid] : 0;
    sm[threadIdx.x] = v;
    __syncthreads();
    for (int off = 1; off < SCAN_B; off <<= 1) {
        int t = (threadIdx.x >= off) ? sm[threadIdx.x - off] : 0;
        __syncthreads();
        sm[threadIdx.x] += t;
        __syncthreads();
    }
    if (gid < N) excl[gid] = sm[threadIdx.x] - v;
    if (threadIdx.x == SCAN_B - 1) blockSums[blockIdx.x] = sm[threadIdx.x];
}

__global__ void k_scan_sums(int* __restrict__ blockSums, int nb) {
    __shared__ int sm[SCAN_B];
    int v = (threadIdx.x < nb) ? blockSums[threadIdx.x] : 0;
    sm[threadIdx.x] = v;
    __syncthreads();
    for (int off = 1; off < SCAN_B; off <<= 1) {
        int t = (threadIdx.x >= off) ? sm[threadIdx.x - off] : 0;
        __syncthreads();
        sm[threadIdx.x] += t;
        __syncthreads();
    }
    if (threadIdx.x < nb) blockSums[threadIdx.x] = sm[threadIdx.x] - v;  // exclusive
}

__global__ void k_add_offsets(const int* __restrict__ excl, const int* __restrict__ blockSums,
                              int* __restrict__ rowstart, int* __restrict__ cursor, int N) {
    int gid = blockIdx.x * SCAN_B + threadIdx.x;
    if (gid < N) {
        int r = excl[gid] + blockSums[blockIdx.x];
        rowstart[gid] = r;
        cursor[gid] = r;
    }
}

// ---------- CSR fill: eid[pos] = src, grouped by dst ----------
__global__ void k_fill(const int* __restrict__ src, const int* __restrict__ dst,
                       int* __restrict__ cursor, int* __restrict__ eid, int E) {
    int e = blockIdx.x * blockDim.x + threadIdx.x;
    if (e < E) {
        int pos = atomicAdd(&cursor[dst[e]], 1);
        eid[pos] = src[e];
    }
}

// ---------- g[n][c] = (h[n,:] @ W[:,c]) * dinv[n] ----------
__global__ void k_gemm_scale(const float* __restrict__ h, const float* __restrict__ W,
                             const float* __restrict__ dinv, float* __restrict__ g, int N) {
    __shared__ float Wl[DFEAT * DFEAT];
    int tid = threadIdx.x;
    #pragma unroll
    for (int i = 0; i < 16; ++i) Wl[tid + i * 256] = W[tid + i * 256];
    __syncthreads();

    int row = blockIdx.x * 4 + (tid >> 6);
    int col = tid & 63;
    if (row >= N) return;

    const float4* h4 = reinterpret_cast<const float4*>(h + (size_t)row * DFEAT);
    float s = 0.f;
    #pragma unroll
    for (int k4 = 0; k4 < 16; ++k4) {
        float4 hv = h4[k4];  // wave-uniform -> broadcast
        s += hv.x * Wl[(k4 * 4 + 0) * 64 + col];
        s += hv.y * Wl[(k4 * 4 + 1) * 64 + col];
        s += hv.z * Wl[(k4 * 4 + 2) * 64 + col];
        s += hv.w * Wl[(k4 * 4 + 3) * 64 + col];
    }
    g[row * DFEAT + col] = s * dinv[row];
}

// ---------- pull-aggregate + finalize: hout = relu(dinv*(g[n] + sum g[src]) + b) ----------
__global__ void k_aggregate(const float* __restrict__ g, const int* __restrict__ rowstart,
                            const int* __restrict__ deg, const int* __restrict__ eid,
                            const float* __restrict__ dinv, const float* __restrict__ b,
                            float* __restrict__ hout, int N) {
    int tid = blockIdx.x * blockDim.x + threadIdx.x;
    int node = tid >> 4, q = tid & 15;
    if (node >= N) return;

    const float4* g4 = reinterpret_cast<const float4*>(g);
    float4 a = g4[node * 16 + q];  // self-loop term (already dinv[n]-scaled)
    int s0 = rowstart[node];
    int d = deg[node];
    for (int i = 0; i < d; ++i) {
        int s = eid[s0 + i];
        float4 v = g4[s * 16 + q];
        a.x += v.x; a.y += v.y; a.z += v.z; a.w += v.w;
    }
    float di = dinv[node];
    float4 bb = reinterpret_cast<const float4*>(b)[q];
    float4 r;
    r.x = fmaxf(fmaf(di, a.x, bb.x), 0.f);
    r.y = fmaxf(fmaf(di, a.y, bb.y), 0.f);
    r.z = fmaxf(fmaf(di, a.z, bb.z), 0.f);
    r.w = fmaxf(fmaf(di, a.w, bb.w), 0.f);
    reinterpret_cast<float4*>(hout)[node * 16 + q] = r;
}

extern "C" void kernel_launch(void* const* d_in, const int* in_sizes, int n_in,
                              void* d_out, int out_size, void* d_ws, size_t ws_size,
                              hipStream_t stream) {
    const float* x  = (const float*)d_in[0];
    const float* W1 = (const float*)d_in[1];
    const float* b1 = (const float*)d_in[2];
    const float* W2 = (const float*)d_in[3];
    const float* b2 = (const float*)d_in[4];
    const float* W3 = (const float*)d_in[5];
    const float* b3 = (const float*)d_in[6];
    const int* eidx = (const int*)d_in[7];  // int64 under default JAX -> int32

    const int N = in_sizes[0] / DFEAT;   // 100000
    const int E = in_sizes[7] / 2;       // 1000000
    const int* esrc = eidx;
    const int* edst = eidx + E;

    // workspace layout
    char* wp = (char*)d_ws;
    int*   deg       = (int*)wp;              wp += (size_t)N * 4;
    float* dinv      = (float*)wp;            wp += (size_t)N * 4;
    int*   excl      = (int*)wp;              wp += (size_t)N * 4;
    int*   blockSums = (int*)wp;              wp += (size_t)SCAN_B * 4;
    int*   rowstart  = (int*)wp;              wp += (size_t)N * 4;
    int*   cursor    = (int*)wp;              wp += (size_t)N * 4;
    int*   eid       = (int*)wp;              wp += (size_t)E * 4;
    float* g         = (float*)wp;            wp += (size_t)N * DFEAT * 4;
    float* hbuf      = (float*)wp;            wp += (size_t)N * DFEAT * 4;
    float* out = (float*)d_out;

    const int B = 256;
    const int nScanBlocks = (N + SCAN_B - 1) / SCAN_B;  // 98

    // ---- CSR build (once, reused 3x) ----
    k_zero_deg<<<(N + B - 1) / B, B, 0, stream>>>(deg, N);
    k_hist<<<(E + B - 1) / B, B, 0, stream>>>(edst, deg, E);
    k_dinv<<<(N + B - 1) / B, B, 0, stream>>>(deg, dinv, N);
    k_scan_block<<<nScanBlocks, SCAN_B, 0, stream>>>(deg, excl, blockSums, N);
    k_scan_sums<<<1, SCAN_B, 0, stream>>>(blockSums, nScanBlocks);
    k_add_offsets<<<nScanBlocks, SCAN_B, 0, stream>>>(excl, blockSums, rowstart, cursor, N);
    k_fill<<<(E + B - 1) / B, B, 0, stream>>>(esrc, edst, cursor, eid, E);

    const int gemm_grid = (N + 3) / 4;
    const int agg_grid  = (N * 16 + B - 1) / B;

    // layer 1
    k_gemm_scale<<<gemm_grid, B, 0, stream>>>(x, W1, dinv, g, N);
    k_aggregate<<<agg_grid, B, 0, stream>>>(g, rowstart, deg, eid, dinv, b1, hbuf, N);
    // layer 2
    k_gemm_scale<<<gemm_grid, B, 0, stream>>>(hbuf, W2, dinv, g, N);
    k_aggregate<<<agg_grid, B, 0, stream>>>(g, rowstart, deg, eid, dinv, b2, hbuf, N);
    // layer 3
    k_gemm_scale<<<gemm_grid, B, 0, stream>>>(hbuf, W3, dinv, g, N);
    k_aggregate<<<agg_grid, B, 0, stream>>>(g, rowstart, deg, eid, dinv, b3, out, N);
}

// Round 3
// 380.109 us; speedup vs baseline: 7.0809x; 1.1919x over previous
//
#include <hip/hip_runtime.h>

#define DFEAT 64
#define SCAN_B 1024

__device__ __forceinline__ float bf2f(unsigned short u) {
    return __uint_as_float(((unsigned)u) << 16);
}
__device__ __forceinline__ unsigned short f2bf(float f) {
    unsigned u = __float_as_uint(f);
    return (unsigned short)((u + 0x7FFFu + ((u >> 16) & 1u)) >> 16);  // RNE
}

// ---------- degree ----------
__global__ void k_zero_deg(int* __restrict__ deg, int N) {
    int i = blockIdx.x * blockDim.x + threadIdx.x;
    if (i < N) deg[i] = 0;
}

// histogram + per-edge rank (rank write is sequential/cheap)
__global__ void k_hist(const int* __restrict__ dst, int* __restrict__ deg,
                       int* __restrict__ rank, int E) {
    int e = blockIdx.x * blockDim.x + threadIdx.x;
    if (e < E) rank[e] = atomicAdd(&deg[dst[e]], 1);
}

__global__ void k_dinv(const int* __restrict__ deg, float* __restrict__ dinv, int N) {
    int i = blockIdx.x * blockDim.x + threadIdx.x;
    if (i < N) dinv[i] = rsqrtf(1.0f + (float)deg[i]);  // +1 = self-loop
}

// ---------- exclusive scan of deg -> rowstart ----------
__global__ void k_scan_block(const int* __restrict__ deg, int* __restrict__ excl,
                             int* __restrict__ blockSums, int N) {
    __shared__ int sm[SCAN_B];
    int gid = blockIdx.x * SCAN_B + threadIdx.x;
    int v = (gid < N) ? deg[gid] : 0;
    sm[threadIdx.x] = v;
    __syncthreads();
    for (int off = 1; off < SCAN_B; off <<= 1) {
        int t = (threadIdx.x >= off) ? sm[threadIdx.x - off] : 0;
        __syncthreads();
        sm[threadIdx.x] += t;
        __syncthreads();
    }
    if (gid < N) excl[gid] = sm[threadIdx.x] - v;
    if (threadIdx.x == SCAN_B - 1) blockSums[blockIdx.x] = sm[threadIdx.x];
}

__global__ void k_scan_sums(int* __restrict__ blockSums, int nb) {
    __shared__ int sm[SCAN_B];
    int v = (threadIdx.x < nb) ? blockSums[threadIdx.x] : 0;
    sm[threadIdx.x] = v;
    __syncthreads();
    for (int off = 1; off < SCAN_B; off <<= 1) {
        int t = (threadIdx.x >= off) ? sm[threadIdx.x - off] : 0;
        __syncthreads();
        sm[threadIdx.x] += t;
        __syncthreads();
    }
    if (threadIdx.x < nb) blockSums[threadIdx.x] = sm[threadIdx.x] - v;  // exclusive
}

__global__ void k_add_offsets(const int* __restrict__ excl, const int* __restrict__ blockSums,
                              int* __restrict__ rowstart, int N, int E) {
    int gid = blockIdx.x * SCAN_B + threadIdx.x;
    if (gid < N) rowstart[gid] = excl[gid] + blockSums[blockIdx.x];
    else if (gid == N) rowstart[N] = E;
}

// ---------- CSR fill (no atomics): eid[rowstart[dst]+rank] = src ----------
__global__ void k_fill(const int* __restrict__ src, const int* __restrict__ dst,
                       const int* __restrict__ rank, const int* __restrict__ rowstart,
                       int* __restrict__ eid, int E) {
    int e = blockIdx.x * blockDim.x + threadIdx.x;
    if (e < E) eid[rowstart[dst[e]] + rank[e]] = src[e];
}

// ---------- g_bf[n][c] = bf16((h[n,:] @ W[:,c]) * dinv[n]) ----------
__global__ void k_gemm_scale(const float* __restrict__ h, const float* __restrict__ W,
                             const float* __restrict__ dinv,
                             unsigned short* __restrict__ gbf, int N) {
    __shared__ float Wl[DFEAT * DFEAT];
    int tid = threadIdx.x;
    #pragma unroll
    for (int i = 0; i < 16; ++i) Wl[tid + i * 256] = W[tid + i * 256];
    __syncthreads();

    int row = blockIdx.x * 4 + (tid >> 6);
    int col = tid & 63;
    if (row >= N) return;

    const float4* h4 = reinterpret_cast<const float4*>(h + (size_t)row * DFEAT);
    float s = 0.f;
    #pragma unroll
    for (int k4 = 0; k4 < 16; ++k4) {
        float4 hv = h4[k4];  // wave-uniform -> broadcast
        s += hv.x * Wl[(k4 * 4 + 0) * 64 + col];
        s += hv.y * Wl[(k4 * 4 + 1) * 64 + col];
        s += hv.z * Wl[(k4 * 4 + 2) * 64 + col];
        s += hv.w * Wl[(k4 * 4 + 3) * 64 + col];
    }
    gbf[(size_t)row * DFEAT + col] = f2bf(s * dinv[row]);
}

// ---------- pull-aggregate, 1 wave = 1 node, lane = feature ----------
__global__ void k_aggregate(const unsigned short* __restrict__ g,
                            const int* __restrict__ rowstart, const int* __restrict__ eid,
                            const float* __restrict__ dinv, const float* __restrict__ b,
                            float* __restrict__ hout, int N) {
    int node = (blockIdx.x * blockDim.x + threadIdx.x) >> 6;
    int lane = threadIdx.x & 63;
    if (node >= N) return;

    int s0 = __builtin_amdgcn_readfirstlane(rowstart[node]);
    int s1 = __builtin_amdgcn_readfirstlane(rowstart[node + 1]);

    float acc = bf2f(g[(size_t)node * DFEAT + lane]);  // self-loop term
    int i = s0;
    for (; i + 4 <= s1; i += 4) {
        int sa = eid[i], sb = eid[i + 1], sc = eid[i + 2], sd = eid[i + 3];
        float va = bf2f(g[(size_t)sa * DFEAT + lane]);
        float vb = bf2f(g[(size_t)sb * DFEAT + lane]);
        float vc = bf2f(g[(size_t)sc * DFEAT + lane]);
        float vd = bf2f(g[(size_t)sd * DFEAT + lane]);
        acc += (va + vb) + (vc + vd);
    }
    for (; i < s1; ++i) acc += bf2f(g[(size_t)eid[i] * DFEAT + lane]);

    hout[(size_t)node * DFEAT + lane] = fmaxf(fmaf(dinv[node], acc, b[lane]), 0.f);
}

extern "C" void kernel_launch(void* const* d_in, const int* in_sizes, int n_in,
                              void* d_out, int out_size, void* d_ws, size_t ws_size,
                              hipStream_t stream) {
    const float* x  = (const float*)d_in[0];
    const float* W1 = (const float*)d_in[1];
    const float* b1 = (const float*)d_in[2];
    const float* W2 = (const float*)d_in[3];
    const float* b2 = (const float*)d_in[4];
    const float* W3 = (const float*)d_in[5];
    const float* b3 = (const float*)d_in[6];
    const int* eidx = (const int*)d_in[7];  // int64 under default JAX -> int32

    const int N = in_sizes[0] / DFEAT;   // 100000
    const int E = in_sizes[7] / 2;       // 1000000
    const int* esrc = eidx;
    const int* edst = eidx + E;

    // workspace layout
    char* wp = (char*)d_ws;
    int*   deg       = (int*)wp;              wp += (size_t)N * 4;
    float* dinv      = (float*)wp;            wp += (size_t)N * 4;
    int*   excl      = (int*)wp;              wp += (size_t)N * 4;
    int*   blockSums = (int*)wp;              wp += (size_t)SCAN_B * 4;
    int*   rowstart  = (int*)wp;              wp += (size_t)(N + 1) * 4;
    int*   rank      = (int*)wp;              wp += (size_t)E * 4;
    int*   eid       = (int*)wp;              wp += (size_t)E * 4;
    unsigned short* gbf = (unsigned short*)wp; wp += (size_t)N * DFEAT * 2;
    float* hbuf      = (float*)wp;            wp += (size_t)N * DFEAT * 4;
    float* out = (float*)d_out;

    const int B = 256;
    const int nScanBlocks = (N + SCAN_B) / SCAN_B + 1;  // covers gid==N

    // ---- CSR build (once, reused 3x) ----
    k_zero_deg<<<(N + B - 1) / B, B, 0, stream>>>(deg, N);
    k_hist<<<(E + B - 1) / B, B, 0, stream>>>(edst, deg, rank, E);
    k_dinv<<<(N + B - 1) / B, B, 0, stream>>>(deg, dinv, N);
    k_scan_block<<<(N + SCAN_B - 1) / SCAN_B, SCAN_B, 0, stream>>>(deg, excl, blockSums, N);
    k_scan_sums<<<1, SCAN_B, 0, stream>>>(blockSums, (N + SCAN_B - 1) / SCAN_B);
    k_add_offsets<<<nScanBlocks, SCAN_B, 0, stream>>>(excl, blockSums, rowstart, N, E);
    k_fill<<<(E + B - 1) / B, B, 0, stream>>>(esrc, edst, rank, rowstart, eid, E);

    const int gemm_grid = (N + 3) / 4;
    const int agg_grid  = (N + 3) / 4;  // 4 waves (nodes) per 256-thread block

    // layer 1
    k_gemm_scale<<<gemm_grid, B, 0, stream>>>(x, W1, dinv, gbf, N);
    k_aggregate<<<agg_grid, B, 0, stream>>>(gbf, rowstart, eid, dinv, b1, hbuf, N);
    // layer 2
    k_gemm_scale<<<gemm_grid, B, 0, stream>>>(hbuf, W2, dinv, gbf, N);
    k_aggregate<<<agg_grid, B, 0, stream>>>(gbf, rowstart, eid, dinv, b2, hbuf, N);
    // layer 3
    k_gemm_scale<<<gemm_grid, B, 0, stream>>>(hbuf, W3, dinv, gbf, N);
    k_aggregate<<<agg_grid, B, 0, stream>>>(gbf, rowstart, eid, dinv, b3, out, N);
}